// Round 7
// baseline (514.550 us; speedup 1.0000x reference)
//
#include <hip/hip_runtime.h>
#include <stdint.h>

// AM-softmax loss, fused on MI355X (gfx950) — round 15.
//
// vs round 14 (203.9 us; gemm 85.4 at MfmaUtil 40.4 / FETCH 22 MB):
//  * Budget model across r9-r14 closes only with a FIXED ~80 us harness/
//    graph overhead (residuals <1 us). Optimizable kernel time is ~124 us:
//    gemm 85.4 + prep ~36 + finalize ~3.
//  * finalize fused into gemm: completion counter; the LAST real block
//    (of 4184) computes the per-row losses from rowsum/aux and stores
//    out[0]. No spinning — single atomic fetch_add check. Kills launch 3.
//  * prep_all W-branch: all 12 float4 loads hoisted into registers before
//    any cvt/store -> guaranteed 12-deep MLP per wave (r14 form risked
//    serial load-latency rounds). Target prep 36 -> ~25 us.
//  * gemm core untouched (proven; at its 2-barrier structural ceiling).

constexpr int N  = 2048;
constexpr int D  = 192;               // K
constexpr int C  = 100000;
constexpr int KT = D / 32;            // 6 k-tiles of 32
constexpr int TILE = 512;             // elems per 16x32 fragment tile
constexpr int RT16 = C / 16;          // 6250 real 16-col tiles
constexpr int TPG = 12;               // 16-col tiles per block (4 waves x 3)
constexpr int CX = 523;               // col groups: 523*12 = 6276 tiles
constexpr int NT16 = CX * TPG;        // 6276 tiles = 100416 cols
constexpr float PHANTOM = (float)(NT16 * 16 - C);   // 416 exact ones
constexpr int BANDS = 4;              // 64-row bands per block
constexpr int RYB = N / (64 * BANDS); // 8 row groups
constexpr int BUF = 4 * KT * TILE;    // 12288 ushort = 24 KB per band buffer
constexpr int NXB = N / 4;            // 512 prep_x blocks
constexpr int CXP = 528;              // cx padded to multiple of 8 (XCD remap)
constexpr int REAL_BLOCKS = CX * RYB; // 4184 non-phantom gemm blocks

#define S_SCALE 30.0f
#define MARGIN  0.2f
#define S_LOG2E 43.2808512266689f     // 30 * log2(e)

using short8 = __attribute__((ext_vector_type(8))) short;   // 8 bf16 (4 VGPRs)
using f32x4  = __attribute__((ext_vector_type(4))) float;   // MFMA C/D

typedef __attribute__((address_space(1))) const void GV;
typedef __attribute__((address_space(3))) void LV;

__device__ inline unsigned short f2bf(float f) {  // fp32 -> bf16 RNE
  unsigned int u = __float_as_uint(f);
  u += 0x7fffu + ((u >> 16) & 1u);
  return (unsigned short)(u >> 16);
}

__device__ inline unsigned int cvtpk(float lo, float hi) {  // RNE pack, = f2bf
  unsigned int r;
  asm("v_cvt_pk_bf16_f32 %0, %1, %2" : "=v"(r) : "v"(lo), "v"(hi));
  return r;
}

// packed fragment index (ushort units) for element (row r, k):
// tile (r>>4, k>>5), lane = (r&15) + ((k>>3)&3)*16, elem k&7.
__device__ inline int pack_idx(int r, int k) {
  return ((r >> 4) * KT + (k >> 5)) * TILE + (((k >> 3) & 3) * 16 + (r & 15)) * 8 + (k & 7);
}

// Sum across each 16-lane DPP row; result valid in all 16 lanes.
__device__ inline float row_sum16(float v) {
  int x;
  x = __float_as_int(v);
  v += __int_as_float(__builtin_amdgcn_update_dpp(0, x, 0x128, 0xF, 0xF, true)); // row_ror:8
  x = __float_as_int(v);
  v += __int_as_float(__builtin_amdgcn_update_dpp(0, x, 0x124, 0xF, 0xF, true)); // row_ror:4
  x = __float_as_int(v);
  v += __int_as_float(__builtin_amdgcn_update_dpp(0, x, 0x04E, 0xF, 0xF, true)); // quad_perm xor2
  x = __float_as_int(v);
  v += __int_as_float(__builtin_amdgcn_update_dpp(0, x, 0x0B1, 0xF, 0xF, true)); // quad_perm xor1
  return v;
}

// ---------------- fused prep: x-normalize+pack + target logit + W pack ----
__global__ __launch_bounds__(256) void prep_all(
    const float* __restrict__ x, const float* __restrict__ W,
    const int* __restrict__ label,
    unsigned short* __restrict__ xnb, unsigned short* __restrict__ Wb,
    float* __restrict__ aux, float* __restrict__ rowsum,
    unsigned int* __restrict__ cnt, float* __restrict__ out) {
  const int bid  = blockIdx.x;
  const int lane = threadIdx.x & 63;
  if (bid == 0 && threadIdx.x == 0) { out[0] = 0.0f; *cnt = 0u; }

  if (bid < NXB) {
    // ---- one wave per x row: normalize + pack + target logit ----
    const int row = bid * 4 + (threadIdx.x >> 6);
    const float* xr = x + (size_t)row * D;
    float v0 = xr[lane], v1 = xr[lane + 64], v2 = xr[lane + 128];
    float ss = v0 * v0 + v1 * v1 + v2 * v2;
    const int lab = label[row];
    const float* wr = W + (size_t)lab * D;
    float d = v0 * wr[lane] + v1 * wr[lane + 64] + v2 * wr[lane + 128];
#pragma unroll
    for (int off = 32; off > 0; off >>= 1) {
      ss += __shfl_xor(ss, off, 64);
      d  += __shfl_xor(d,  off, 64);
    }
    const float rinv = rsqrtf(ss);
    const float inv = rinv * S_LOG2E;
    xnb[pack_idx(row, lane)]       = f2bf(v0 * inv);
    xnb[pack_idx(row, lane + 64)]  = f2bf(v1 * inv);
    xnb[pack_idx(row, lane + 128)] = f2bf(v2 * inv);
    if (lane == 0) {
      aux[row]    = d * rinv;   // target logit (unscaled)
      rowsum[row] = 0.0f;       // accumulator for gemm atomics
    }
  } else {
    // ---- one wave per 16-col W tile; tiles >= RT16 exactly zero ----
    const int t16 = (bid - NXB) * 4 + (threadIdx.x >> 6);
    const int m = lane & 15, q = lane >> 4;
    unsigned short* dst = Wb + (size_t)t16 * KT * TILE + lane * 8;
    if (t16 < RT16) {
      const float* src = W + (size_t)(t16 * 16 + m) * D + q * 8;
      // hoist ALL loads first -> 12-deep MLP per wave (one latency round)
      float4 f[2 * KT];
#pragma unroll
      for (int ks = 0; ks < KT; ++ks) {
        const float4* s4 = (const float4*)(src + ks * 32);
        f[2 * ks]     = s4[0];
        f[2 * ks + 1] = s4[1];
      }
#pragma unroll
      for (int ks = 0; ks < KT; ++ks) {
        union { uint4 u; short8 s; } cv;
        cv.u.x = cvtpk(f[2 * ks].x,     f[2 * ks].y);
        cv.u.y = cvtpk(f[2 * ks].z,     f[2 * ks].w);
        cv.u.z = cvtpk(f[2 * ks + 1].x, f[2 * ks + 1].y);
        cv.u.w = cvtpk(f[2 * ks + 1].z, f[2 * ks + 1].w);
        *(short8*)(dst + (size_t)ks * TILE) = cv.s;
      }
    } else {
      const short8 z = {0, 0, 0, 0, 0, 0, 0, 0};
#pragma unroll
      for (int ks = 0; ks < KT; ++ks) *(short8*)(dst + (size_t)ks * TILE) = z;
    }
  }
}

// ---------------- main fused GEMM + exp-rowsum + last-block finalize ------
// Grid CXP*RYB (4224). XCD-aware map (proven): xcd=bid&7, j=bid>>3, ry=j&7,
// cx=(j>>3)*8+xcd. Block = 4 waves; wave owns 48 cols (breg from packed Wb).
// 4 bands of 64 rows, A double-buffered, DMA prefetch one band ahead.
// Epilogue: per-row exp-sums atomicAdd into rowsum[N]. The LAST real block
// to finish (completion counter) computes all 2048 row losses and writes
// out[0] -- no third kernel launch.
__global__ __launch_bounds__(256, 3) void gemm_lse(
    const unsigned short* __restrict__ xnb,  // packed [128 row-tiles][KT][512]
    const unsigned short* __restrict__ Wb,   // packed [NT16][KT][512]
    const float* __restrict__ aux,           // [N] target logits
    float* __restrict__ rowsum,              // [N] atomic accumulator
    unsigned int* __restrict__ cnt,          // completion counter
    float* __restrict__ out) {
  __shared__ alignas(16) unsigned short As[2 * BUF];   // 48 KB (double buffer)
  __shared__ alignas(16) float rs_lds[4][256];         // 4 KB
  __shared__ int last_flag;

  const int tid = threadIdx.x;
  const int bid = blockIdx.x;
  const int xcd = bid & 7, j = bid >> 3;
  const int ry = j & 7;
  const int cx = (j >> 3) * 8 + xcd;
  if (cx >= CX) return;                     // 40 phantom blocks (pad to 528)

  // ---- issue DMA for band 0 into buf 0 (24 KB, contiguous packed) ----
  {
    const unsigned short* slab = xnb + (size_t)(ry * BANDS) * BUF;
#pragma unroll
    for (int i = 0; i < 6; ++i) {            // 1536 x 16 B
      const int chunk = tid + i * 256;
      __builtin_amdgcn_global_load_lds(
          (GV*)((const char*)slab + (size_t)chunk * 16),
          (LV*)((char*)As + (size_t)chunk * 16), 16, 0, 0);
    }
  }

  const int lane = tid & 63, wave = tid >> 6;
  const int m = lane & 15, quad = lane >> 4;

  // ---- B fragments from packed Wb (18 coalesced 1 KB wave-loads) ----
  short8 breg[3][KT];
#pragma unroll
  for (int tc = 0; tc < 3; ++tc)
#pragma unroll
    for (int ks = 0; ks < KT; ++ks)
      breg[tc][ks] = *(const short8*)(
          Wb + (size_t)((cx * TPG + wave * 3 + tc) * KT + ks) * TILE + lane * 8);

  const f32x4 zero4 = {0.0f, 0.0f, 0.0f, 0.0f};

  for (int b = 0; b < BANDS; ++b) {
    __syncthreads();   // drains vmcnt: band b's DMA (issued a full band ago)

    // prefetch band b+1 into the other buffer BEFORE compute of band b
    if (b + 1 < BANDS) {
      const unsigned short* slab = xnb + (size_t)(ry * BANDS + b + 1) * BUF;
      char* dst = (char*)&As[((b + 1) & 1) * BUF];
#pragma unroll
      for (int i = 0; i < 6; ++i) {
        const int chunk = tid + i * 256;
        __builtin_amdgcn_global_load_lds(
            (GV*)((const char*)slab + (size_t)chunk * 16),
            (LV*)(dst + (size_t)chunk * 16), 16, 0, 0);
      }
    }

    const unsigned short* Ab = &As[(b & 1) * BUF];

    f32x4 acc[4][3];
#pragma unroll
    for (int a = 0; a < 4; ++a)
#pragma unroll
      for (int c = 0; c < 3; ++c) acc[a][c] = zero4;

#pragma unroll
    for (int ks = 0; ks < KT; ++ks) {
      short8 af[4];
#pragma unroll
      for (int tr = 0; tr < 4; ++tr)
        af[tr] = *(const short8*)(&Ab[(tr * KT + ks) * TILE + lane * 8]);
#pragma unroll
      for (int tr = 0; tr < 4; ++tr)
#pragma unroll
        for (int tc = 0; tc < 3; ++tc)
          acc[tr][tc] = __builtin_amdgcn_mfma_f32_16x16x32_bf16(
              af[tr], breg[tc][ks], acc[tr][tc], 0, 0, 0);
    }

    // ---- epilogue: exp2 (arg pre-scaled; phantom cols give exactly 1) ----
#pragma unroll
    for (int tr = 0; tr < 4; ++tr) {
      float rv0 = 0.f, rv1 = 0.f, rv2 = 0.f, rv3 = 0.f;
#pragma unroll
      for (int tc = 0; tc < 3; ++tc) {
        rv0 += __builtin_amdgcn_exp2f(acc[tr][tc][0]);
        rv1 += __builtin_amdgcn_exp2f(acc[tr][tc][1]);
        rv2 += __builtin_amdgcn_exp2f(acc[tr][tc][2]);
        rv3 += __builtin_amdgcn_exp2f(acc[tr][tc][3]);
      }
      rv0 = row_sum16(rv0);
      rv1 = row_sum16(rv1);
      rv2 = row_sum16(rv2);
      rv3 = row_sum16(rv3);
      if (m == 0) {
        float4 v = make_float4(rv0, rv1, rv2, rv3);
        *(float4*)(&rs_lds[wave][b * 64 + tr * 16 + quad * 4]) = v;
      }
    }
  }

  __syncthreads();  // all waves' rowsums in LDS
  const float s = rs_lds[0][tid] + rs_lds[1][tid] + rs_lds[2][tid] + rs_lds[3][tid];
  atomicAdd(&rowsum[ry * 256 + tid], s);    // 523 adds/address, spread in time

  // ---- completion counter; last real block computes the loss ----
  __threadfence();                          // release our rowsum adds
  __syncthreads();                          // (also drains this block's vmem)
  if (tid == 0) {
    const unsigned int p = __hip_atomic_fetch_add(
        cnt, 1u, __ATOMIC_ACQ_REL, __HIP_MEMORY_SCOPE_AGENT);
    last_flag = (p == (unsigned int)(REAL_BLOCKS - 1));
  }
  __syncthreads();
  if (last_flag) {
    __threadfence();                        // acquire: invalidate stale lines
    float L = 0.0f;
    for (int r = tid; r < N; r += 256) {
      const float rsv = __hip_atomic_load(&rowsum[r], __ATOMIC_RELAXED,
                                          __HIP_MEMORY_SCOPE_AGENT);
      const float tgt   = aux[r];
      const float numer = S_SCALE * (tgt - MARGIN);
      // remove phantom-ones, swap label column's exp for margin-adjusted exp
      const float se = rsv - PHANTOM - __expf(S_SCALE * tgt) + __expf(numer);
      L += numer - logf(se);
    }
#pragma unroll
    for (int off = 32; off > 0; off >>= 1) L += __shfl_xor(L, off, 64);
    if (lane == 0) rs_lds[0][wave] = L;
    __syncthreads();
    if (tid == 0)
      out[0] = -(rs_lds[0][0] + rs_lds[0][1] + rs_lds[0][2] + rs_lds[0][3]) *
               (1.0f / (float)N);
  }
}

// ---------------- host ----------------------------------------------------
extern "C" void kernel_launch(void* const* d_in, const int* in_sizes, int n_in,
                              void* d_out, int out_size, void* d_ws, size_t ws_size,
                              hipStream_t stream) {
  const float* x     = (const float*)d_in[0];
  const float* W     = (const float*)d_in[1];
  const int*   label = (const int*)d_in[2];
  float*       out   = (float*)d_out;

  char* ws = (char*)d_ws;
  size_t off = 0;
  unsigned short* xnb = (unsigned short*)(ws + off); off += (size_t)N * D * 2;            // 768 KB
  unsigned short* Wb  = (unsigned short*)(ws + off); off += (size_t)NT16 * KT * TILE * 2; // 38.6 MB
  float* aux    = (float*)(ws + off); off += (size_t)N * 4;                                // 8 KB
  float* rowsum = (float*)(ws + off); off += (size_t)N * 4;                                // 8 KB
  unsigned int* cnt = (unsigned int*)(ws + off); off += 128;                               // counter

  prep_all<<<NXB + NT16 / 4, 256, 0, stream>>>(x, W, label, xnb, Wb, aux, rowsum, cnt, out);

  gemm_lse<<<CXP * RYB, 256, 0, stream>>>(xnb, Wb, aux, rowsum, cnt, out);
}

// Round 8
// 202.282 us; speedup vs baseline: 2.5437x; 2.5437x over previous
//
#include <hip/hip_runtime.h>
#include <stdint.h>

// AM-softmax loss, fused on MI355X (gfx950) — round 16.
//
// vs round 15 (FAILED perf: gemm 415 us, MfmaUtil 7.7): the per-block
// __threadfence() (seq_cst agent fence -> buffer_wbl2 + buffer_inv) ran in
// all 4184 blocks and invalidated each XCD's L2 continuously -> all
// concurrent blocks lost Wb/xnb L2 residency (latency hit; FETCH unchanged
// because L3 absorbed it). RULE: no device-scope fences in the hot path.
// Reverted to r14's proven 3-kernel structure (203.9 us).
//
// vs round 14 (gemm 85.4 us, MfmaUtil 40.4 / VALUBusy 45.2):
//  * Per-band budget: 72 MFMA ~ 350cy vs epilogue (48 v_exp_f32 TRANS +
//    adds + DPP row-sums) ~ 320-450cy, fully serialized after the MFMAs.
//    MFMA and VALU/TRANS are separate pipes -> pipeline the epilogue:
//    band b's epilogue is placed textually after band b+1's K-loop inside
//    the same barrier-free region, so the scheduler interleaves exp2/DPP
//    with the MFMA stream.
//  * Half-band granularity (32 rows): two acc sets of 2x3 f32x4 (24 regs
//    each, 48 total = SAME acc footprint as r14 -> no occupancy risk),
//    alternating accA/accB, every K-half followed by the EPI of the
//    previous half. All names static, fully unrolled.
//  * Barriers, DMA prefetch timing, breg-from-Wb, atomic rowsum epilogue,
//    prep_all (hoisted 12-deep loads), finalize_tiny: unchanged from
//    r14/r15-prep.

constexpr int N  = 2048;
constexpr int D  = 192;               // K
constexpr int C  = 100000;
constexpr int KT = D / 32;            // 6 k-tiles of 32
constexpr int TILE = 512;             // elems per 16x32 fragment tile
constexpr int RT16 = C / 16;          // 6250 real 16-col tiles
constexpr int TPG = 12;               // 16-col tiles per block (4 waves x 3)
constexpr int CX = 523;               // col groups: 523*12 = 6276 tiles
constexpr int NT16 = CX * TPG;        // 6276 tiles = 100416 cols
constexpr float PHANTOM = (float)(NT16 * 16 - C);   // 416 exact ones
constexpr int BANDS = 4;              // 64-row bands per block
constexpr int RYB = N / (64 * BANDS); // 8 row groups
constexpr int BUF = 4 * KT * TILE;    // 12288 ushort = 24 KB per band buffer
constexpr int NXB = N / 4;            // 512 prep_x blocks
constexpr int CXP = 528;              // cx padded to multiple of 8 (XCD remap)

#define S_SCALE 30.0f
#define MARGIN  0.2f
#define S_LOG2E 43.2808512266689f     // 30 * log2(e)

using short8 = __attribute__((ext_vector_type(8))) short;   // 8 bf16 (4 VGPRs)
using f32x4  = __attribute__((ext_vector_type(4))) float;   // MFMA C/D

typedef __attribute__((address_space(1))) const void GV;
typedef __attribute__((address_space(3))) void LV;

__device__ inline unsigned short f2bf(float f) {  // fp32 -> bf16 RNE
  unsigned int u = __float_as_uint(f);
  u += 0x7fffu + ((u >> 16) & 1u);
  return (unsigned short)(u >> 16);
}

__device__ inline unsigned int cvtpk(float lo, float hi) {  // RNE pack, = f2bf
  unsigned int r;
  asm("v_cvt_pk_bf16_f32 %0, %1, %2" : "=v"(r) : "v"(lo), "v"(hi));
  return r;
}

// packed fragment index (ushort units) for element (row r, k):
// tile (r>>4, k>>5), lane = (r&15) + ((k>>3)&3)*16, elem k&7.
__device__ inline int pack_idx(int r, int k) {
  return ((r >> 4) * KT + (k >> 5)) * TILE + (((k >> 3) & 3) * 16 + (r & 15)) * 8 + (k & 7);
}

// Sum across each 16-lane DPP row; result valid in all 16 lanes.
__device__ inline float row_sum16(float v) {
  int x;
  x = __float_as_int(v);
  v += __int_as_float(__builtin_amdgcn_update_dpp(0, x, 0x128, 0xF, 0xF, true)); // row_ror:8
  x = __float_as_int(v);
  v += __int_as_float(__builtin_amdgcn_update_dpp(0, x, 0x124, 0xF, 0xF, true)); // row_ror:4
  x = __float_as_int(v);
  v += __int_as_float(__builtin_amdgcn_update_dpp(0, x, 0x04E, 0xF, 0xF, true)); // quad_perm xor2
  x = __float_as_int(v);
  v += __int_as_float(__builtin_amdgcn_update_dpp(0, x, 0x0B1, 0xF, 0xF, true)); // quad_perm xor1
  return v;
}

// ---------------- fused prep: x-normalize+pack + target logit + W pack ----
__global__ __launch_bounds__(256) void prep_all(
    const float* __restrict__ x, const float* __restrict__ W,
    const int* __restrict__ label,
    unsigned short* __restrict__ xnb, unsigned short* __restrict__ Wb,
    float* __restrict__ aux, float* __restrict__ rowsum,
    float* __restrict__ out) {
  const int bid  = blockIdx.x;
  const int lane = threadIdx.x & 63;
  if (bid == 0 && threadIdx.x == 0) out[0] = 0.0f;   // for finalize atomic

  if (bid < NXB) {
    // ---- one wave per x row: normalize + pack + target logit ----
    const int row = bid * 4 + (threadIdx.x >> 6);
    const float* xr = x + (size_t)row * D;
    float v0 = xr[lane], v1 = xr[lane + 64], v2 = xr[lane + 128];
    float ss = v0 * v0 + v1 * v1 + v2 * v2;
    const int lab = label[row];
    const float* wr = W + (size_t)lab * D;
    float d = v0 * wr[lane] + v1 * wr[lane + 64] + v2 * wr[lane + 128];
#pragma unroll
    for (int off = 32; off > 0; off >>= 1) {
      ss += __shfl_xor(ss, off, 64);
      d  += __shfl_xor(d,  off, 64);
    }
    const float rinv = rsqrtf(ss);
    const float inv = rinv * S_LOG2E;
    xnb[pack_idx(row, lane)]       = f2bf(v0 * inv);
    xnb[pack_idx(row, lane + 64)]  = f2bf(v1 * inv);
    xnb[pack_idx(row, lane + 128)] = f2bf(v2 * inv);
    if (lane == 0) {
      aux[row]    = d * rinv;   // target logit (unscaled)
      rowsum[row] = 0.0f;       // accumulator for gemm atomics
    }
  } else {
    // ---- one wave per 16-col W tile; tiles >= RT16 exactly zero ----
    const int t16 = (bid - NXB) * 4 + (threadIdx.x >> 6);
    const int m = lane & 15, q = lane >> 4;
    unsigned short* dst = Wb + (size_t)t16 * KT * TILE + lane * 8;
    if (t16 < RT16) {
      const float* src = W + (size_t)(t16 * 16 + m) * D + q * 8;
      // hoist ALL loads first -> 12-deep MLP per wave (one latency round)
      float4 f[2 * KT];
#pragma unroll
      for (int ks = 0; ks < KT; ++ks) {
        const float4* s4 = (const float4*)(src + ks * 32);
        f[2 * ks]     = s4[0];
        f[2 * ks + 1] = s4[1];
      }
#pragma unroll
      for (int ks = 0; ks < KT; ++ks) {
        union { uint4 u; short8 s; } cv;
        cv.u.x = cvtpk(f[2 * ks].x,     f[2 * ks].y);
        cv.u.y = cvtpk(f[2 * ks].z,     f[2 * ks].w);
        cv.u.z = cvtpk(f[2 * ks + 1].x, f[2 * ks + 1].y);
        cv.u.w = cvtpk(f[2 * ks + 1].z, f[2 * ks + 1].w);
        *(short8*)(dst + (size_t)ks * TILE) = cv.s;
      }
    } else {
      const short8 z = {0, 0, 0, 0, 0, 0, 0, 0};
#pragma unroll
      for (int ks = 0; ks < KT; ++ks) *(short8*)(dst + (size_t)ks * TILE) = z;
    }
  }
}

// issue one 24 KB band DMA into buffer (BN&1)
#define PREFETCH(BN)                                                          \
  {                                                                           \
    const unsigned short* slab = xnb + (size_t)(ry * BANDS + (BN)) * BUF;     \
    char* dst = (char*)&As[((BN) & 1) * BUF];                                 \
    _Pragma("unroll")                                                         \
    for (int i = 0; i < 6; ++i) {                                             \
      const int chunk = tid + i * 256;                                        \
      __builtin_amdgcn_global_load_lds(                                       \
          (GV*)((const char*)slab + (size_t)chunk * 16),                      \
          (LV*)(dst + (size_t)chunk * 16), 16, 0, 0);                         \
    }                                                                         \
  }

// K-loop over one 32-row half of a band: 36 MFMA into ACC[2][3]
#define KH(BIDX, H, ACC)                                                      \
  {                                                                           \
    const unsigned short* Ab = &As[((BIDX) & 1) * BUF];                       \
    _Pragma("unroll")                                                         \
    for (int t2 = 0; t2 < 2; ++t2)                                            \
      _Pragma("unroll")                                                       \
      for (int c = 0; c < 3; ++c) ACC[t2][c] = zero4;                         \
    _Pragma("unroll")                                                         \
    for (int ks = 0; ks < KT; ++ks) {                                         \
      const short8 af0 =                                                      \
          *(const short8*)(&Ab[(((H) * 2 + 0) * KT + ks) * TILE + lane * 8]); \
      const short8 af1 =                                                      \
          *(const short8*)(&Ab[(((H) * 2 + 1) * KT + ks) * TILE + lane * 8]); \
      _Pragma("unroll")                                                       \
      for (int c = 0; c < 3; ++c)                                             \
        ACC[0][c] = __builtin_amdgcn_mfma_f32_16x16x32_bf16(                  \
            af0, breg[c][ks], ACC[0][c], 0, 0, 0);                            \
      _Pragma("unroll")                                                       \
      for (int c = 0; c < 3; ++c)                                             \
        ACC[1][c] = __builtin_amdgcn_mfma_f32_16x16x32_bf16(                  \
            af1, breg[c][ks], ACC[1][c], 0, 0, 0);                            \
    }                                                                         \
  }

// epilogue of one half-band: exp2 sums + DPP row-reduce + rs_lds store.
// Placed textually AFTER the next half's KH so the scheduler interleaves
// its VALU/TRANS ops with the MFMA stream (separate pipes).
#define EPI(ACC, BIDX, H)                                                     \
  {                                                                           \
    _Pragma("unroll")                                                         \
    for (int t2 = 0; t2 < 2; ++t2) {                                          \
      float rv0 = 0.f, rv1 = 0.f, rv2 = 0.f, rv3 = 0.f;                       \
      _Pragma("unroll")                                                       \
      for (int c = 0; c < 3; ++c) {                                           \
        rv0 += __builtin_amdgcn_exp2f(ACC[t2][c][0]);                         \
        rv1 += __builtin_amdgcn_exp2f(ACC[t2][c][1]);                         \
        rv2 += __builtin_amdgcn_exp2f(ACC[t2][c][2]);                         \
        rv3 += __builtin_amdgcn_exp2f(ACC[t2][c][3]);                         \
      }                                                                       \
      rv0 = row_sum16(rv0);                                                   \
      rv1 = row_sum16(rv1);                                                   \
      rv2 = row_sum16(rv2);                                                   \
      rv3 = row_sum16(rv3);                                                   \
      if (m == 0)                                                             \
        *(float4*)(&rs_lds[wave][(BIDX) * 64 + (H) * 32 + t2 * 16 + quad * 4]) = \
            make_float4(rv0, rv1, rv2, rv3);                                  \
    }                                                                         \
  }

// ---------------- main fused GEMM + exp-rowsum ----------------------------
// Grid CXP*RYB (4224). XCD-aware map (proven): xcd=bid&7, j=bid>>3, ry=j&7,
// cx=(j>>3)*8+xcd -> 8 ry-blocks of one cx share one XCD's L2 (Wb panel
// fetched once). Block = 4 waves; wave owns 48 cols (breg from packed Wb).
// 4 bands x 2 half-bands, software-pipelined epilogue, A double-buffered,
// DMA prefetch one band ahead. Per-row exp-sums atomicAdd into rowsum[N].
__global__ __launch_bounds__(256, 3) void gemm_lse(
    const unsigned short* __restrict__ xnb,  // packed [128 row-tiles][KT][512]
    const unsigned short* __restrict__ Wb,   // packed [NT16][KT][512]
    float* __restrict__ rowsum) {            // [N] atomic accumulator
  __shared__ alignas(16) unsigned short As[2 * BUF];   // 48 KB (double buffer)
  __shared__ alignas(16) float rs_lds[4][256];         // 4 KB

  const int tid = threadIdx.x;
  const int bid = blockIdx.x;
  const int xcd = bid & 7, j = bid >> 3;
  const int ry = j & 7;
  const int cx = (j >> 3) * 8 + xcd;
  if (cx >= CX) return;                     // 40 phantom blocks (pad to 528)

  // ---- issue DMA for band 0 into buf 0 (24 KB, contiguous packed) ----
  {
    const unsigned short* slab = xnb + (size_t)(ry * BANDS) * BUF;
#pragma unroll
    for (int i = 0; i < 6; ++i) {            // 1536 x 16 B
      const int chunk = tid + i * 256;
      __builtin_amdgcn_global_load_lds(
          (GV*)((const char*)slab + (size_t)chunk * 16),
          (LV*)((char*)As + (size_t)chunk * 16), 16, 0, 0);
    }
  }

  const int lane = tid & 63, wave = tid >> 6;
  const int m = lane & 15, quad = lane >> 4;

  // ---- B fragments from packed Wb (18 coalesced 1 KB wave-loads) ----
  short8 breg[3][KT];
#pragma unroll
  for (int tc = 0; tc < 3; ++tc)
#pragma unroll
    for (int ks = 0; ks < KT; ++ks)
      breg[tc][ks] = *(const short8*)(
          Wb + (size_t)((cx * TPG + wave * 3 + tc) * KT + ks) * TILE + lane * 8);

  const f32x4 zero4 = {0.0f, 0.0f, 0.0f, 0.0f};
  f32x4 accA[2][3], accB[2][3];

  // ---- pipelined band schedule: EPI(half h) overlaps KH(half h+1) ----
  // band 0
  __syncthreads();                 // drains band-0 DMA
  PREFETCH(1);
  KH(0, 0, accA);
  KH(0, 1, accB); EPI(accA, 0, 0);
  // band 1
  __syncthreads();                 // drains band-1 DMA (covered by band 0)
  PREFETCH(2);
  KH(1, 0, accA); EPI(accB, 0, 1);
  KH(1, 1, accB); EPI(accA, 1, 0);
  // band 2
  __syncthreads();
  PREFETCH(3);
  KH(2, 0, accA); EPI(accB, 1, 1);
  KH(2, 1, accB); EPI(accA, 2, 0);
  // band 3
  __syncthreads();
  KH(3, 0, accA); EPI(accB, 2, 1);
  KH(3, 1, accB); EPI(accA, 3, 0);
  EPI(accB, 3, 1);

  __syncthreads();  // all waves' rowsums in LDS
  const float s = rs_lds[0][tid] + rs_lds[1][tid] + rs_lds[2][tid] + rs_lds[3][tid];
  atomicAdd(&rowsum[ry * 256 + tid], s);    // 523 adds/address, spread in time
}

// ---------------- finalize: per-row loss + in-kernel mean reduce ----------
// 8 blocks x 256 threads, one thread per row. Reads are fully coalesced.
__global__ __launch_bounds__(256) void finalize_tiny(
    const float* __restrict__ aux, const float* __restrict__ rowsum,
    float* __restrict__ out) {
  const int row  = blockIdx.x * 256 + threadIdx.x;
  const int lane = threadIdx.x & 63, wave = threadIdx.x >> 6;
  const float tgt   = aux[row];
  const float numer = S_SCALE * (tgt - MARGIN);
  // remove phantom-ones, swap label column's exp for margin-adjusted exp
  const float se = rowsum[row] - PHANTOM - __expf(S_SCALE * tgt) + __expf(numer);
  float L = numer - logf(se);
#pragma unroll
  for (int off = 32; off > 0; off >>= 1) L += __shfl_xor(L, off, 64);
  __shared__ float part[4];
  if (lane == 0) part[wave] = L;
  __syncthreads();
  if (threadIdx.x == 0) {
    const float blocksum = part[0] + part[1] + part[2] + part[3];
    atomicAdd(out, -blocksum * (1.0f / (float)N));
  }
}

// ---------------- host ----------------------------------------------------
extern "C" void kernel_launch(void* const* d_in, const int* in_sizes, int n_in,
                              void* d_out, int out_size, void* d_ws, size_t ws_size,
                              hipStream_t stream) {
  const float* x     = (const float*)d_in[0];
  const float* W     = (const float*)d_in[1];
  const int*   label = (const int*)d_in[2];
  float*       out   = (float*)d_out;

  char* ws = (char*)d_ws;
  size_t off = 0;
  unsigned short* xnb = (unsigned short*)(ws + off); off += (size_t)N * D * 2;            // 768 KB
  unsigned short* Wb  = (unsigned short*)(ws + off); off += (size_t)NT16 * KT * TILE * 2; // 38.6 MB
  float* aux    = (float*)(ws + off); off += (size_t)N * 4;                                // 8 KB
  float* rowsum = (float*)(ws + off); off += (size_t)N * 4;                                // 8 KB

  prep_all<<<NXB + NT16 / 4, 256, 0, stream>>>(x, W, label, xnb, Wb, aux, rowsum, out);

  gemm_lse<<<CXP * RYB, 256, 0, stream>>>(xnb, Wb, rowsum);

  finalize_tiny<<<N / 256, 256, 0, stream>>>(aux, rowsum, out);
}

// Round 9
// 198.464 us; speedup vs baseline: 2.5927x; 1.0192x over previous
//
#include <hip/hip_runtime.h>
#include <stdint.h>

// AM-softmax loss, fused on MI355X (gfx950) — round 17.
//
// vs round 16 (202.3 us; gemm 84.0, MfmaUtil 40.8, VALUBusy 47, Occ 28%):
//  * r16's intra-wave EPI/KH pipelining was ~null (85.4->84.0) — consistent
//    with m114: MFMA and VALU pipes fill via CROSS-WAVE TLP, not per-wave
//    ILP. At 3 blocks/CU with barrier-locked waves, phase diversity is the
//    limit. This round buys a 4th resident block:
//    - bands 64 -> 32 rows (8 bands): LDS dbuf 2x12 KB -> 28 KB/block
//      (was 52) -> LDS allows 5 blocks/CU.
//    - dual accumulator dropped (it bought ~1.5 us): acc[2][3] = 24 regs,
//      -24 VGPR -> ~120 total fits __launch_bounds__(256,4) without spill
//      -> 4 blocks/CU (VGPR-limited).
//    - finer bands also desync blocks at 36-MFMA granularity.
//  * Grid/XCD map/DMA chain/prep/finalize/atomic-rowsum: unchanged.

constexpr int N  = 2048;
constexpr int D  = 192;               // K
constexpr int C  = 100000;
constexpr int KT = D / 32;            // 6 k-tiles of 32
constexpr int TILE = 512;             // elems per 16x32 fragment tile
constexpr int RT16 = C / 16;          // 6250 real 16-col tiles
constexpr int TPG = 12;               // 16-col tiles per block (4 waves x 3)
constexpr int CX = 523;               // col groups: 523*12 = 6276 tiles
constexpr int NT16 = CX * TPG;        // 6276 tiles = 100416 cols
constexpr float PHANTOM = (float)(NT16 * 16 - C);   // 416 exact ones
constexpr int BANDS = 8;              // 32-row bands per block (256 rows)
constexpr int RYB = N / (32 * BANDS); // 8 row groups
constexpr int BUF = 2 * KT * TILE;    // 6144 ushort = 12 KB per band buffer
constexpr int NXB = N / 4;            // 512 prep_x blocks
constexpr int CXP = 528;              // cx padded to multiple of 8 (XCD remap)

#define S_SCALE 30.0f
#define MARGIN  0.2f
#define S_LOG2E 43.2808512266689f     // 30 * log2(e)

using short8 = __attribute__((ext_vector_type(8))) short;   // 8 bf16 (4 VGPRs)
using f32x4  = __attribute__((ext_vector_type(4))) float;   // MFMA C/D

typedef __attribute__((address_space(1))) const void GV;
typedef __attribute__((address_space(3))) void LV;

__device__ inline unsigned short f2bf(float f) {  // fp32 -> bf16 RNE
  unsigned int u = __float_as_uint(f);
  u += 0x7fffu + ((u >> 16) & 1u);
  return (unsigned short)(u >> 16);
}

__device__ inline unsigned int cvtpk(float lo, float hi) {  // RNE pack, = f2bf
  unsigned int r;
  asm("v_cvt_pk_bf16_f32 %0, %1, %2" : "=v"(r) : "v"(lo), "v"(hi));
  return r;
}

// packed fragment index (ushort units) for element (row r, k):
// tile (r>>4, k>>5), lane = (r&15) + ((k>>3)&3)*16, elem k&7.
__device__ inline int pack_idx(int r, int k) {
  return ((r >> 4) * KT + (k >> 5)) * TILE + (((k >> 3) & 3) * 16 + (r & 15)) * 8 + (k & 7);
}

// Sum across each 16-lane DPP row; result valid in all 16 lanes.
__device__ inline float row_sum16(float v) {
  int x;
  x = __float_as_int(v);
  v += __int_as_float(__builtin_amdgcn_update_dpp(0, x, 0x128, 0xF, 0xF, true)); // row_ror:8
  x = __float_as_int(v);
  v += __int_as_float(__builtin_amdgcn_update_dpp(0, x, 0x124, 0xF, 0xF, true)); // row_ror:4
  x = __float_as_int(v);
  v += __int_as_float(__builtin_amdgcn_update_dpp(0, x, 0x04E, 0xF, 0xF, true)); // quad_perm xor2
  x = __float_as_int(v);
  v += __int_as_float(__builtin_amdgcn_update_dpp(0, x, 0x0B1, 0xF, 0xF, true)); // quad_perm xor1
  return v;
}

// ---------------- fused prep: x-normalize+pack + target logit + W pack ----
__global__ __launch_bounds__(256) void prep_all(
    const float* __restrict__ x, const float* __restrict__ W,
    const int* __restrict__ label,
    unsigned short* __restrict__ xnb, unsigned short* __restrict__ Wb,
    float* __restrict__ aux, float* __restrict__ rowsum,
    float* __restrict__ out) {
  const int bid  = blockIdx.x;
  const int lane = threadIdx.x & 63;
  if (bid == 0 && threadIdx.x == 0) out[0] = 0.0f;   // for finalize atomic

  if (bid < NXB) {
    // ---- one wave per x row: normalize + pack + target logit ----
    const int row = bid * 4 + (threadIdx.x >> 6);
    const float* xr = x + (size_t)row * D;
    float v0 = xr[lane], v1 = xr[lane + 64], v2 = xr[lane + 128];
    float ss = v0 * v0 + v1 * v1 + v2 * v2;
    const int lab = label[row];
    const float* wr = W + (size_t)lab * D;
    float d = v0 * wr[lane] + v1 * wr[lane + 64] + v2 * wr[lane + 128];
#pragma unroll
    for (int off = 32; off > 0; off >>= 1) {
      ss += __shfl_xor(ss, off, 64);
      d  += __shfl_xor(d,  off, 64);
    }
    const float rinv = rsqrtf(ss);
    const float inv = rinv * S_LOG2E;
    xnb[pack_idx(row, lane)]       = f2bf(v0 * inv);
    xnb[pack_idx(row, lane + 64)]  = f2bf(v1 * inv);
    xnb[pack_idx(row, lane + 128)] = f2bf(v2 * inv);
    if (lane == 0) {
      aux[row]    = d * rinv;   // target logit (unscaled)
      rowsum[row] = 0.0f;       // accumulator for gemm atomics
    }
  } else {
    // ---- one wave per 16-col W tile; tiles >= RT16 exactly zero ----
    const int t16 = (bid - NXB) * 4 + (threadIdx.x >> 6);
    const int m = lane & 15, q = lane >> 4;
    unsigned short* dst = Wb + (size_t)t16 * KT * TILE + lane * 8;
    if (t16 < RT16) {
      const float* src = W + (size_t)(t16 * 16 + m) * D + q * 8;
      // hoist ALL loads first -> 12-deep MLP per wave (one latency round)
      float4 f[2 * KT];
#pragma unroll
      for (int ks = 0; ks < KT; ++ks) {
        const float4* s4 = (const float4*)(src + ks * 32);
        f[2 * ks]     = s4[0];
        f[2 * ks + 1] = s4[1];
      }
#pragma unroll
      for (int ks = 0; ks < KT; ++ks) {
        union { uint4 u; short8 s; } cv;
        cv.u.x = cvtpk(f[2 * ks].x,     f[2 * ks].y);
        cv.u.y = cvtpk(f[2 * ks].z,     f[2 * ks].w);
        cv.u.z = cvtpk(f[2 * ks + 1].x, f[2 * ks + 1].y);
        cv.u.w = cvtpk(f[2 * ks + 1].z, f[2 * ks + 1].w);
        *(short8*)(dst + (size_t)ks * TILE) = cv.s;
      }
    } else {
      const short8 z = {0, 0, 0, 0, 0, 0, 0, 0};
#pragma unroll
      for (int ks = 0; ks < KT; ++ks) *(short8*)(dst + (size_t)ks * TILE) = z;
    }
  }
}

// issue one 12 KB band DMA into buffer (BN&1): 768 x 16 B over 256 threads
#define PREFETCH(BN)                                                          \
  {                                                                           \
    const unsigned short* slab = xnb + (size_t)(ry * BANDS + (BN)) * BUF;     \
    char* dst = (char*)&As[((BN) & 1) * BUF];                                 \
    _Pragma("unroll")                                                         \
    for (int i = 0; i < 3; ++i) {                                             \
      const int chunk = tid + i * 256;                                        \
      __builtin_amdgcn_global_load_lds(                                       \
          (GV*)((const char*)slab + (size_t)chunk * 16),                      \
          (LV*)(dst + (size_t)chunk * 16), 16, 0, 0);                         \
    }                                                                         \
  }

// ---------------- main fused GEMM + exp-rowsum ----------------------------
// Grid CXP*RYB (4224). XCD-aware map (proven): xcd=bid&7, j=bid>>3, ry=j&7,
// cx=(j>>3)*8+xcd -> 8 ry-blocks of one cx share one XCD's L2 (Wb panel
// fetched once). Block = 4 waves; wave owns 48 cols (breg from packed Wb).
// 8 bands of 32 rows, A double-buffered (12 KB each), DMA prefetch one band
// ahead. LDS 28 KB + <=128 VGPR -> 4 blocks/CU (was 3): cross-wave TLP
// fills MFMA+VALU pipes. Per-row exp-sums atomicAdd into rowsum[N].
__global__ __launch_bounds__(256, 4) void gemm_lse(
    const unsigned short* __restrict__ xnb,  // packed [128 row-tiles][KT][512]
    const unsigned short* __restrict__ Wb,   // packed [NT16][KT][512]
    float* __restrict__ rowsum) {            // [N] atomic accumulator
  __shared__ alignas(16) unsigned short As[2 * BUF];   // 24 KB (double buffer)
  __shared__ alignas(16) float rs_lds[4][256];         // 4 KB

  const int tid = threadIdx.x;
  const int bid = blockIdx.x;
  const int xcd = bid & 7, j = bid >> 3;
  const int ry = j & 7;
  const int cx = (j >> 3) * 8 + xcd;
  if (cx >= CX) return;                     // 40 phantom blocks (pad to 528)

  // ---- issue DMA for band 0 into buf 0 (12 KB, contiguous packed) ----
  {
    const unsigned short* slab = xnb + (size_t)(ry * BANDS) * BUF;
#pragma unroll
    for (int i = 0; i < 3; ++i) {            // 768 x 16 B
      const int chunk = tid + i * 256;
      __builtin_amdgcn_global_load_lds(
          (GV*)((const char*)slab + (size_t)chunk * 16),
          (LV*)((char*)As + (size_t)chunk * 16), 16, 0, 0);
    }
  }

  const int lane = tid & 63, wave = tid >> 6;
  const int m = lane & 15, quad = lane >> 4;

  // ---- B fragments from packed Wb (18 coalesced 1 KB wave-loads) ----
  short8 breg[3][KT];
#pragma unroll
  for (int tc = 0; tc < 3; ++tc)
#pragma unroll
    for (int ks = 0; ks < KT; ++ks)
      breg[tc][ks] = *(const short8*)(
          Wb + (size_t)((cx * TPG + wave * 3 + tc) * KT + ks) * TILE + lane * 8);

  const f32x4 zero4 = {0.0f, 0.0f, 0.0f, 0.0f};

#pragma unroll
  for (int b = 0; b < BANDS; ++b) {        // fully unrolled: b compile-time
    __syncthreads();   // drains vmcnt: band b's DMA (issued one band ago)

    if (b + 1 < BANDS) PREFETCH(b + 1);

    const unsigned short* Ab = &As[(b & 1) * BUF];

    f32x4 acc[2][3];
#pragma unroll
    for (int t2 = 0; t2 < 2; ++t2)
#pragma unroll
      for (int c = 0; c < 3; ++c) acc[t2][c] = zero4;

#pragma unroll
    for (int ks = 0; ks < KT; ++ks) {
      const short8 af0 = *(const short8*)(&Ab[(0 * KT + ks) * TILE + lane * 8]);
      const short8 af1 = *(const short8*)(&Ab[(1 * KT + ks) * TILE + lane * 8]);
#pragma unroll
      for (int c = 0; c < 3; ++c)
        acc[0][c] = __builtin_amdgcn_mfma_f32_16x16x32_bf16(
            af0, breg[c][ks], acc[0][c], 0, 0, 0);
#pragma unroll
      for (int c = 0; c < 3; ++c)
        acc[1][c] = __builtin_amdgcn_mfma_f32_16x16x32_bf16(
            af1, breg[c][ks], acc[1][c], 0, 0, 0);
    }

    // ---- epilogue: exp2 (arg pre-scaled; phantom cols give exactly 1) ----
#pragma unroll
    for (int t2 = 0; t2 < 2; ++t2) {
      float rv0 = 0.f, rv1 = 0.f, rv2 = 0.f, rv3 = 0.f;
#pragma unroll
      for (int c = 0; c < 3; ++c) {
        rv0 += __builtin_amdgcn_exp2f(acc[t2][c][0]);
        rv1 += __builtin_amdgcn_exp2f(acc[t2][c][1]);
        rv2 += __builtin_amdgcn_exp2f(acc[t2][c][2]);
        rv3 += __builtin_amdgcn_exp2f(acc[t2][c][3]);
      }
      rv0 = row_sum16(rv0);
      rv1 = row_sum16(rv1);
      rv2 = row_sum16(rv2);
      rv3 = row_sum16(rv3);
      if (m == 0)
        *(float4*)(&rs_lds[wave][b * 32 + t2 * 16 + quad * 4]) =
            make_float4(rv0, rv1, rv2, rv3);
    }
  }

  __syncthreads();  // all waves' rowsums in LDS
  const float s = rs_lds[0][tid] + rs_lds[1][tid] + rs_lds[2][tid] + rs_lds[3][tid];
  atomicAdd(&rowsum[ry * 256 + tid], s);    // 523 adds/address, spread in time
}

// ---------------- finalize: per-row loss + in-kernel mean reduce ----------
// 8 blocks x 256 threads, one thread per row. Reads are fully coalesced.
__global__ __launch_bounds__(256) void finalize_tiny(
    const float* __restrict__ aux, const float* __restrict__ rowsum,
    float* __restrict__ out) {
  const int row  = blockIdx.x * 256 + threadIdx.x;
  const int lane = threadIdx.x & 63, wave = threadIdx.x >> 6;
  const float tgt   = aux[row];
  const float numer = S_SCALE * (tgt - MARGIN);
  // remove phantom-ones, swap label column's exp for margin-adjusted exp
  const float se = rowsum[row] - PHANTOM - __expf(S_SCALE * tgt) + __expf(numer);
  float L = numer - logf(se);
#pragma unroll
  for (int off = 32; off > 0; off >>= 1) L += __shfl_xor(L, off, 64);
  __shared__ float part[4];
  if (lane == 0) part[wave] = L;
  __syncthreads();
  if (threadIdx.x == 0) {
    const float blocksum = part[0] + part[1] + part[2] + part[3];
    atomicAdd(out, -blocksum * (1.0f / (float)N));
  }
}

// ---------------- host ----------------------------------------------------
extern "C" void kernel_launch(void* const* d_in, const int* in_sizes, int n_in,
                              void* d_out, int out_size, void* d_ws, size_t ws_size,
                              hipStream_t stream) {
  const float* x     = (const float*)d_in[0];
  const float* W     = (const float*)d_in[1];
  const int*   label = (const int*)d_in[2];
  float*       out   = (float*)d_out;

  char* ws = (char*)d_ws;
  size_t off = 0;
  unsigned short* xnb = (unsigned short*)(ws + off); off += (size_t)N * D * 2;            // 768 KB
  unsigned short* Wb  = (unsigned short*)(ws + off); off += (size_t)NT16 * KT * TILE * 2; // 38.6 MB
  float* aux    = (float*)(ws + off); off += (size_t)N * 4;                                // 8 KB
  float* rowsum = (float*)(ws + off); off += (size_t)N * 4;                                // 8 KB

  prep_all<<<NXB + NT16 / 4, 256, 0, stream>>>(x, W, label, xnb, Wb, aux, rowsum, out);

  gemm_lse<<<CXP * RYB, 256, 0, stream>>>(xnb, Wb, rowsum);

  finalize_tiny<<<N / 256, 256, 0, stream>>>(aux, rowsum, out);
}